// Round 10
// baseline (521.468 us; speedup 1.0000x reference)
//
#include <hip/hip_runtime.h>
#include <hip/hip_bf16.h>
#include <cstdint>

typedef __attribute__((ext_vector_type(8))) short short8v;
typedef __attribute__((ext_vector_type(4))) short short4v;
typedef __attribute__((ext_vector_type(4))) float f32x4;

__device__ __forceinline__ float4 add4(float4 a, float4 b) {
  return make_float4(a.x + b.x, a.y + b.y, a.z + b.z, a.w + b.w);
}
__device__ __forceinline__ float bf2f(unsigned short u) {
  union { unsigned int i; float f; } v; v.i = ((unsigned int)u) << 16; return v.f;
}
__device__ __forceinline__ unsigned short f2bf(float f) {
  union { float f; unsigned int i; } v; v.f = f;
  unsigned int r = v.i + 0x7fff + ((v.i >> 16) & 1);
  return (unsigned short)(r >> 16);
}
__device__ __forceinline__ float4 shflx4(float4 a, int m) {
  return make_float4(__shfl_xor(a.x, m, 64), __shfl_xor(a.y, m, 64),
                     __shfl_xor(a.z, m, 64), __shfl_xor(a.w, m, 64));
}
__device__ __forceinline__ void acc8(float4& lo, float4& hi, short8v v) {
  lo.x += bf2f((unsigned short)v[0]); lo.y += bf2f((unsigned short)v[1]);
  lo.z += bf2f((unsigned short)v[2]); lo.w += bf2f((unsigned short)v[3]);
  hi.x += bf2f((unsigned short)v[4]); hi.y += bf2f((unsigned short)v[5]);
  hi.z += bf2f((unsigned short)v[6]); hi.w += bf2f((unsigned short)v[7]);
}

// ---------------- prep: count_deg + f2bf + weight pack, one launch ----------------
__global__ __launch_bounds__(256) void prep_kernel(
    const int* __restrict__ dst, int* __restrict__ deg, int E,
    const float* __restrict__ x_in, unsigned short* __restrict__ x_bf, int nx8,
    const float* __restrict__ We0, const float* __restrict__ Wr0,
    const float* __restrict__ We1, const float* __restrict__ Wr1,
    const float* __restrict__ We2, const float* __restrict__ Wr2,
    unsigned short* __restrict__ Wt0, unsigned short* __restrict__ Wt1,
    unsigned short* __restrict__ Wt2) {
  int gs = gridDim.x * 256;
  int gid = blockIdx.x * 256 + threadIdx.x;
  for (int i = gid; i < E; i += gs) atomicAdd(&deg[dst[i]], 1);
  for (int i = gid; i < nx8; i += gs) {
    float4 v0 = *(const float4*)(x_in + i * 8);
    float4 v1 = *(const float4*)(x_in + i * 8 + 4);
    short8v o;
    o[0] = (short)f2bf(v0.x); o[1] = (short)f2bf(v0.y);
    o[2] = (short)f2bf(v0.z); o[3] = (short)f2bf(v0.w);
    o[4] = (short)f2bf(v1.x); o[5] = (short)f2bf(v1.y);
    o[6] = (short)f2bf(v1.z); o[7] = (short)f2bf(v1.w);
    *(short8v*)(x_bf + i * 8) = o;
  }
  const int p0 = 128 * 192, p1 = 128 * 320;
  for (int idx = gid; idx < p0 + 2 * p1; idx += gs) {
    const float* We; const float* Wr; unsigned short* Wt;
    int rowsE, Ktot, local;
    if (idx < p0) { We = We0; Wr = Wr0; Wt = Wt0; rowsE = 128; Ktot = 192; local = idx; }
    else if (idx < p0 + p1) { We = We1; Wr = Wr1; Wt = Wt1; rowsE = 192; Ktot = 320; local = idx - p0; }
    else { We = We2; Wr = Wr2; Wt = Wt2; rowsE = 192; Ktot = 320; local = idx - p0 - p1; }
    int c = local / Ktot, k = local % Ktot;
    float v = (k < rowsE) ? We[(size_t)k * 128 + c] : Wr[(size_t)(k - rowsE) * 128 + c];
    Wt[local] = f2bf(v);
  }
}

// ---------------- CSR scan trio ----------------
__global__ void block_sum_kernel(const int* __restrict__ deg, int* __restrict__ bsum, int N) {
  int t = threadIdx.x;
  int i = blockIdx.x * 512 + t;
  int v = (i < N) ? deg[i] : 0;
#pragma unroll
  for (int off = 32; off > 0; off >>= 1) v += __shfl_down(v, off, 64);
  __shared__ int ws[8];
  int lane = t & 63, wid = t >> 6;
  if (lane == 0) ws[wid] = v;
  __syncthreads();
  if (t == 0) {
    int s = 0;
#pragma unroll
    for (int j = 0; j < 8; ++j) s += ws[j];
    bsum[blockIdx.x] = s;
  }
}

__global__ void scan_small_kernel(const int* __restrict__ bsum, int* __restrict__ boffs, int B) {
  int t = threadIdx.x;
  int lane = t & 63, wid = t >> 6;
  int v = (t < B) ? bsum[t] : 0;
  int incl = v;
#pragma unroll
  for (int off = 1; off < 64; off <<= 1) {
    int u = __shfl_up(incl, off, 64);
    if (lane >= off) incl += u;
  }
  __shared__ int ws[2];
  if (lane == 63) ws[wid] = incl;
  __syncthreads();
  int base = (wid == 1) ? ws[0] : 0;
  if (t < B) boffs[t] = base + incl - v;
}

__global__ void ptrs_kernel(const int* __restrict__ deg, const int* __restrict__ boffs,
                            int* __restrict__ ptrs, int N) {
  int t = threadIdx.x;
  int i = blockIdx.x * 512 + t;
  int lane = t & 63, wid = t >> 6;
  int v = (i < N) ? deg[i] : 0;
  int incl = v;
#pragma unroll
  for (int off = 1; off < 64; off <<= 1) {
    int u = __shfl_up(incl, off, 64);
    if (lane >= off) incl += u;
  }
  __shared__ int ws[8];
  if (lane == 63) ws[wid] = incl;
  __syncthreads();
  if (t == 0) {
    int s = 0;
#pragma unroll
    for (int j = 0; j < 8; ++j) { int tmp = ws[j]; ws[j] = s; s += tmp; }
  }
  __syncthreads();
  if (i < N) ptrs[i + 1] = boffs[blockIdx.x] + ws[wid] + incl;
  if (i == 0 && blockIdx.x == 0) ptrs[0] = 0;
}

__global__ void fill_csr_kernel(const int* __restrict__ src, const int* __restrict__ dst,
                                const int* __restrict__ ptrs, int* __restrict__ cnt,
                                int* __restrict__ csr_src, int* __restrict__ csr_eid, int E) {
  int i = blockIdx.x * blockDim.x + threadIdx.x;
  if (i < E) {
    int d = dst[i];
    int pos = ptrs[d] + atomicAdd(&cnt[d], 1);
    csr_src[pos] = src[i];
    csr_eid[pos] = i;
  }
}

// ---------------- fused layer: aggregate (per-wave, round-8 structure) + MFMA GEMM ----------------
// 1024 threads = 16 waves; block covers 64 nodes; wave w aggregates nodes w*4..w*4+3 into LDS.
// LDS sA row layout (bf16): L0: [aggx64 | agge64]; layers 1-2: aggx128. First K=128 of the
// GEMM comes from LDS; remaining segments (agge / xprev) from global.
template <int L0, int POOL>
__global__ __launch_bounds__(1024, 8) void fused_layer_kernel(
    const int* __restrict__ ptrs, const int* __restrict__ csr_src, const int* __restrict__ csr_eid,
    const float* __restrict__ ea, const unsigned short* __restrict__ xprev,
    const unsigned short* __restrict__ agge_r, unsigned short* __restrict__ agge_w,
    const unsigned short* __restrict__ Wt, int Ktot,
    const float* __restrict__ be, const float* __restrict__ br,
    const int* __restrict__ deg, const int* __restrict__ batch,
    unsigned short* __restrict__ out, float* __restrict__ pout, int N) {
  int t = threadIdx.x;
  int wv = t >> 6, lane = t & 63;
  int n0 = blockIdx.x * 64;
  __shared__ unsigned short sA[64][136];
  __shared__ unsigned short st[64][136];
  __shared__ int bsh[64];

  const int xw = L0 ? 64 : 128;  // width of xprev rows

  // ---- phase 1: aggregation, 4 nodes per wave ----
  for (int j = 0; j < 4; ++j) {
    int lr = wv * 4 + j;
    int n = n0 + lr;
    int s = 0, e = 0;
    if (n < N) { s = ptrs[n]; e = ptrs[n + 1]; }
    if (L0) {
      int slot_a = lane >> 4, cg_a = lane & 15;
      int slot_b = lane >> 3, cg_b = lane & 7;
      float4 z = make_float4(0, 0, 0, 0);
      float4 a0 = z, a1 = z, xlo = z, xhi = z;
      int i = s;
      for (; i + 8 <= e; i += 8) {
        int e0 = csr_eid[i + slot_a];
        int e1 = csr_eid[i + 4 + slot_a];
        int r0 = csr_src[i + slot_b];
        a0 = add4(a0, *((const float4*)(ea + (size_t)e0 * 64) + cg_a));
        a1 = add4(a1, *((const float4*)(ea + (size_t)e1 * 64) + cg_a));
        acc8(xlo, xhi, *(const short8v*)(xprev + (size_t)r0 * 64 + cg_b * 8));
      }
      if (i + slot_a < e)
        a0 = add4(a0, *((const float4*)(ea + (size_t)csr_eid[i + slot_a] * 64) + cg_a));
      if (i + 4 + slot_a < e)
        a1 = add4(a1, *((const float4*)(ea + (size_t)csr_eid[i + 4 + slot_a] * 64) + cg_a));
      if (i + slot_b < e)
        acc8(xlo, xhi, *(const short8v*)(xprev + (size_t)csr_src[i + slot_b] * 64 + cg_b * 8));
      // ea reduce (4 slots)
      a0 = add4(a0, a1);
      a0 = add4(a0, shflx4(a0, 16));
      a0 = add4(a0, shflx4(a0, 32));
      if (slot_a == 0) {
        short4v o;
        o[0] = (short)f2bf(a0.x); o[1] = (short)f2bf(a0.y);
        o[2] = (short)f2bf(a0.z); o[3] = (short)f2bf(a0.w);
        *(short4v*)(&sA[lr][64 + cg_a * 4]) = o;
        if (n < N) *(short4v*)(agge_w + (size_t)n * 64 + cg_a * 4) = o;
      }
      // x reduce (8 slots)
      xlo = add4(xlo, shflx4(xlo, 8));  xhi = add4(xhi, shflx4(xhi, 8));
      xlo = add4(xlo, shflx4(xlo, 16)); xhi = add4(xhi, shflx4(xhi, 16));
      xlo = add4(xlo, shflx4(xlo, 32)); xhi = add4(xhi, shflx4(xhi, 32));
      if (slot_b == 0) {
        short8v o;
        o[0] = (short)f2bf(xlo.x); o[1] = (short)f2bf(xlo.y);
        o[2] = (short)f2bf(xlo.z); o[3] = (short)f2bf(xlo.w);
        o[4] = (short)f2bf(xhi.x); o[5] = (short)f2bf(xhi.y);
        o[6] = (short)f2bf(xhi.z); o[7] = (short)f2bf(xhi.w);
        *(short8v*)(&sA[lr][cg_b * 8]) = o;
      }
    } else {
      int slot = lane >> 4, cg = lane & 15;
      float4 z = make_float4(0, 0, 0, 0);
      float4 lo0 = z, hi0 = z, lo1 = z, hi1 = z;
      int i = s + slot;
      for (; i + 4 < e; i += 8) {
        acc8(lo0, hi0, *(const short8v*)(xprev + (size_t)csr_src[i] * 128 + cg * 8));
        acc8(lo1, hi1, *(const short8v*)(xprev + (size_t)csr_src[i + 4] * 128 + cg * 8));
      }
      if (i < e) acc8(lo0, hi0, *(const short8v*)(xprev + (size_t)csr_src[i] * 128 + cg * 8));
      lo0 = add4(lo0, lo1); hi0 = add4(hi0, hi1);
      lo0 = add4(lo0, shflx4(lo0, 16)); hi0 = add4(hi0, shflx4(hi0, 16));
      lo0 = add4(lo0, shflx4(lo0, 32)); hi0 = add4(hi0, shflx4(hi0, 32));
      if (slot == 0) {
        short8v o;
        o[0] = (short)f2bf(lo0.x); o[1] = (short)f2bf(lo0.y);
        o[2] = (short)f2bf(lo0.z); o[3] = (short)f2bf(lo0.w);
        o[4] = (short)f2bf(hi0.x); o[5] = (short)f2bf(hi0.y);
        o[6] = (short)f2bf(hi0.z); o[7] = (short)f2bf(hi0.w);
        *(short8v*)(&sA[lr][cg * 8]) = o;
      }
    }
  }
  if (POOL && t < 64) {
    int n = n0 + t;
    bsh[t] = (n < N) ? batch[n] : -1;
  }
  __syncthreads();

  // ---- phase 2: GEMM. wave wv: row tile wv&3, col tiles {(wv>>2)*2, (wv>>2)*2+1} ----
  int rit = lane & 15, kgrp = lane >> 4;
  int rt = wv & 3, cp = wv >> 2;
  int arow_l = rt * 16 + rit;
  int arow_g = n0 + arow_l;
  if (arow_g >= N) arow_g = N - 1;
  f32x4 acc0 = (f32x4){0.f, 0.f, 0.f, 0.f};
  f32x4 acc1 = (f32x4){0.f, 0.f, 0.f, 0.f};
  const unsigned short* WtA = Wt + (size_t)((cp * 2 + 0) * 16 + rit) * Ktot;
  const unsigned short* WtB = Wt + (size_t)((cp * 2 + 1) * 16 + rit) * Ktot;

  // segment 1: LDS, K = 128
#pragma unroll
  for (int kk = 0; kk < 128; kk += 32) {
    int kg = kk + kgrp * 8;
    short8v a = *(const short8v*)(&sA[arow_l][kg]);
    acc0 = __builtin_amdgcn_mfma_f32_16x16x32_bf16(a, *(const short8v*)(WtA + kg), acc0, 0, 0, 0);
    acc1 = __builtin_amdgcn_mfma_f32_16x16x32_bf16(a, *(const short8v*)(WtB + kg), acc1, 0, 0, 0);
  }
  int kbase = 128;
  // segment 2 (layers 1-2 only): agge, K = 64
  if (!L0) {
#pragma unroll
    for (int kk = 0; kk < 64; kk += 32) {
      int kg = kbase + kk + kgrp * 8;
      short8v a = *(const short8v*)(agge_r + (size_t)arow_g * 64 + kk + kgrp * 8);
      acc0 = __builtin_amdgcn_mfma_f32_16x16x32_bf16(a, *(const short8v*)(WtA + kg), acc0, 0, 0, 0);
      acc1 = __builtin_amdgcn_mfma_f32_16x16x32_bf16(a, *(const short8v*)(WtB + kg), acc1, 0, 0, 0);
    }
    kbase += 64;
  }
  // segment 3: xprev (root transform input), K = xw
#pragma unroll
  for (int kk = 0; kk < (L0 ? 64 : 128); kk += 32) {
    int kg = kbase + kk + kgrp * 8;
    short8v a = *(const short8v*)(xprev + (size_t)arow_g * xw + kk + kgrp * 8);
    acc0 = __builtin_amdgcn_mfma_f32_16x16x32_bf16(a, *(const short8v*)(WtA + kg), acc0, 0, 0, 0);
    acc1 = __builtin_amdgcn_mfma_f32_16x16x32_bf16(a, *(const short8v*)(WtB + kg), acc1, 0, 0, 0);
  }

  // epilogue: bias + relu -> st
  float dg[4];
#pragma unroll
  for (int r = 0; r < 4; ++r) {
    int n = n0 + rt * 16 + kgrp * 4 + r;
    dg[r] = (float)deg[n < N ? n : N - 1];
  }
#pragma unroll
  for (int c = 0; c < 2; ++c) {
    int col = (cp * 2 + c) * 16 + rit;
    float bev = be[col], brv = br[col];
    f32x4 a = c ? acc1 : acc0;
#pragma unroll
    for (int r = 0; r < 4; ++r) {
      float v = a[r] + dg[r] * bev + brv;
      st[rt * 16 + kgrp * 4 + r][col] = f2bf(fmaxf(v, 0.f));
    }
  }
  __syncthreads();

  if (POOL) {
    if (t < 128) {
      int c = t;
      float acc2 = 0.f;
      int g = bsh[0];
      for (int r = 0; r < 64; ++r) {
        int n = n0 + r;
        if (n >= N) break;
        int gn = bsh[r];
        if (gn != g) {
          atomicAdd(&pout[g * 128 + c], acc2);
          acc2 = 0.f;
          g = gn;
        }
        acc2 += bf2f(st[r][c]);
      }
      atomicAdd(&pout[g * 128 + c], acc2);
    }
  } else {
    int row = t >> 4, cg = t & 15;
    int n = n0 + row;
    if (n < N)
      *(short8v*)(out + (size_t)n * 128 + cg * 8) = *(const short8v*)(&st[row][cg * 8]);
  }
}

// ---------------- launch ----------------

extern "C" void kernel_launch(void* const* d_in, const int* in_sizes, int n_in,
                              void* d_out, int out_size, void* d_ws, size_t ws_size,
                              hipStream_t stream) {
  const float* x_in       = (const float*)d_in[0];
  const int*   edge_index = (const int*)d_in[1];
  const float* edge_attr  = (const float*)d_in[2];
  const int*   batch      = (const int*)d_in[3];
  const float* We0 = (const float*)d_in[4];
  const float* be0 = (const float*)d_in[5];
  const float* Wr0 = (const float*)d_in[6];
  const float* br0 = (const float*)d_in[7];
  const float* We1 = (const float*)d_in[8];
  const float* be1 = (const float*)d_in[9];
  const float* Wr1 = (const float*)d_in[10];
  const float* br1 = (const float*)d_in[11];
  const float* We2 = (const float*)d_in[12];
  const float* be2 = (const float*)d_in[13];
  const float* Wr2 = (const float*)d_in[14];
  const float* br2 = (const float*)d_in[15];

  float* out = (float*)d_out;

  int N = in_sizes[0] / 64;   // 50000
  int E = in_sizes[1] / 2;    // 1600000
  const int* src = edge_index;
  const int* dst = edge_index + E;

  char* w = (char*)d_ws;
  size_t off = 0;
  auto alloc = [&](size_t bytes) {
    void* p = w + off;
    off += (bytes + 255) & ~(size_t)255;
    return p;
  };
  int* deg     = (int*)alloc((size_t)N * 4);
  int* cnt     = (int*)alloc((size_t)N * 4);
  size_t zero_bytes = off;  // deg + cnt zeroed each call
  int* ptrs    = (int*)alloc((size_t)(N + 1) * 4);
  int* bsum    = (int*)alloc(128 * 4);
  int* boffs   = (int*)alloc(128 * 4);
  int* csr_src = (int*)alloc((size_t)E * 4);
  int* csr_eid = (int*)alloc((size_t)E * 4);
  unsigned short* x_bf = (unsigned short*)alloc((size_t)N * 64 * 2);
  unsigned short* agge = (unsigned short*)alloc((size_t)N * 64 * 2);
  unsigned short* xb0  = (unsigned short*)alloc((size_t)N * 128 * 2);
  unsigned short* xb1  = (unsigned short*)alloc((size_t)N * 128 * 2);
  unsigned short* Wt0  = (unsigned short*)alloc((size_t)128 * 192 * 2);
  unsigned short* Wt1  = (unsigned short*)alloc((size_t)128 * 320 * 2);
  unsigned short* Wt2  = (unsigned short*)alloc((size_t)128 * 320 * 2);

  (void)hipMemsetAsync(d_ws, 0, zero_bytes, stream);
  (void)hipMemsetAsync(d_out, 0, (size_t)out_size * sizeof(float), stream);

  int eb = (E + 255) / 256;
  int sb = (N + 511) / 512;
  prep_kernel<<<2048, 256, 0, stream>>>(dst, deg, E, x_in, x_bf, N * 64 / 8,
                                        We0, Wr0, We1, Wr1, We2, Wr2, Wt0, Wt1, Wt2);
  block_sum_kernel<<<sb, 512, 0, stream>>>(deg, bsum, N);
  scan_small_kernel<<<1, 128, 0, stream>>>(bsum, boffs, sb);
  ptrs_kernel<<<sb, 512, 0, stream>>>(deg, boffs, ptrs, N);
  fill_csr_kernel<<<eb, 256, 0, stream>>>(src, dst, ptrs, cnt, csr_src, csr_eid, E);

  int gb = (N + 63) / 64;
  // Layer 0: agg(ea + x) in LDS, write agge globally, GEMM (Wt0: aggx64|agge|x)
  fused_layer_kernel<1, 0><<<gb, 1024, 0, stream>>>(ptrs, csr_src, csr_eid, edge_attr, x_bf,
                                                    nullptr, agge, Wt0, 192, be0, br0,
                                                    deg, batch, xb0, nullptr, N);
  // Layer 1: agg(xb0) in LDS, GEMM (Wt1: aggx128|agge|xb0)
  fused_layer_kernel<0, 0><<<gb, 1024, 0, stream>>>(ptrs, csr_src, nullptr, nullptr, xb0,
                                                    agge, nullptr, Wt1, 320, be1, br1,
                                                    deg, batch, xb1, nullptr, N);
  // Layer 2 + fused pooling
  fused_layer_kernel<0, 1><<<gb, 1024, 0, stream>>>(ptrs, csr_src, nullptr, nullptr, xb1,
                                                    agge, nullptr, Wt2, 320, be2, br2,
                                                    deg, batch, nullptr, out, N);
}

// Round 11
// 495.276 us; speedup vs baseline: 1.0529x; 1.0529x over previous
//
#include <hip/hip_runtime.h>
#include <hip/hip_bf16.h>
#include <cstdint>

typedef __attribute__((ext_vector_type(8))) short short8v;
typedef __attribute__((ext_vector_type(4))) short short4v;
typedef __attribute__((ext_vector_type(4))) float f32x4;

__device__ __forceinline__ float4 add4(float4 a, float4 b) {
  return make_float4(a.x + b.x, a.y + b.y, a.z + b.z, a.w + b.w);
}
__device__ __forceinline__ float bf2f(unsigned short u) {
  union { unsigned int i; float f; } v; v.i = ((unsigned int)u) << 16; return v.f;
}
__device__ __forceinline__ unsigned short f2bf(float f) {
  union { float f; unsigned int i; } v; v.f = f;
  unsigned int r = v.i + 0x7fff + ((v.i >> 16) & 1);
  return (unsigned short)(r >> 16);
}
__device__ __forceinline__ float4 shflx4(float4 a, int m) {
  return make_float4(__shfl_xor(a.x, m, 64), __shfl_xor(a.y, m, 64),
                     __shfl_xor(a.z, m, 64), __shfl_xor(a.w, m, 64));
}
__device__ __forceinline__ void acc8(float4& lo, float4& hi, short8v v) {
  lo.x += bf2f((unsigned short)v[0]); lo.y += bf2f((unsigned short)v[1]);
  lo.z += bf2f((unsigned short)v[2]); lo.w += bf2f((unsigned short)v[3]);
  hi.x += bf2f((unsigned short)v[4]); hi.y += bf2f((unsigned short)v[5]);
  hi.z += bf2f((unsigned short)v[6]); hi.w += bf2f((unsigned short)v[7]);
}

// ---------------- prep: count_deg + f2bf(x) + weight pack, one launch ----------------
__global__ __launch_bounds__(256) void prep_kernel(
    const int* __restrict__ dst, int* __restrict__ deg, int E,
    const float* __restrict__ x_in, unsigned short* __restrict__ x_bf, int nx8,
    const float* __restrict__ We0, const float* __restrict__ Wr0,
    const float* __restrict__ We1, const float* __restrict__ Wr1,
    const float* __restrict__ We2, const float* __restrict__ Wr2,
    unsigned short* __restrict__ Wt0, unsigned short* __restrict__ Wt1,
    unsigned short* __restrict__ Wt2) {
  int gs = gridDim.x * 256;
  int gid = blockIdx.x * 256 + threadIdx.x;
  for (int i = gid; i < E; i += gs) atomicAdd(&deg[dst[i]], 1);
  for (int i = gid; i < nx8; i += gs) {
    float4 v0 = *(const float4*)(x_in + i * 8);
    float4 v1 = *(const float4*)(x_in + i * 8 + 4);
    short8v o;
    o[0] = (short)f2bf(v0.x); o[1] = (short)f2bf(v0.y);
    o[2] = (short)f2bf(v0.z); o[3] = (short)f2bf(v0.w);
    o[4] = (short)f2bf(v1.x); o[5] = (short)f2bf(v1.y);
    o[6] = (short)f2bf(v1.z); o[7] = (short)f2bf(v1.w);
    *(short8v*)(x_bf + i * 8) = o;
  }
  const int p0 = 128 * 192, p1 = 128 * 320;
  for (int idx = gid; idx < p0 + 2 * p1; idx += gs) {
    const float* We; const float* Wr; unsigned short* Wt;
    int rowsE, Ktot, local;
    if (idx < p0) { We = We0; Wr = Wr0; Wt = Wt0; rowsE = 128; Ktot = 192; local = idx; }
    else if (idx < p0 + p1) { We = We1; Wr = Wr1; Wt = Wt1; rowsE = 192; Ktot = 320; local = idx - p0; }
    else { We = We2; Wr = Wr2; Wt = Wt2; rowsE = 192; Ktot = 320; local = idx - p0 - p1; }
    int c = local / Ktot, k = local % Ktot;
    float v = (k < rowsE) ? We[(size_t)k * 128 + c] : Wr[(size_t)(k - rowsE) * 128 + c];
    Wt[local] = f2bf(v);
  }
}

// ---------------- CSR scan trio + fill ----------------
__global__ void block_sum_kernel(const int* __restrict__ deg, int* __restrict__ bsum, int N) {
  int t = threadIdx.x;
  int i = blockIdx.x * 512 + t;
  int v = (i < N) ? deg[i] : 0;
#pragma unroll
  for (int off = 32; off > 0; off >>= 1) v += __shfl_down(v, off, 64);
  __shared__ int ws[8];
  int lane = t & 63, wid = t >> 6;
  if (lane == 0) ws[wid] = v;
  __syncthreads();
  if (t == 0) {
    int s = 0;
#pragma unroll
    for (int j = 0; j < 8; ++j) s += ws[j];
    bsum[blockIdx.x] = s;
  }
}

__global__ void scan_small_kernel(const int* __restrict__ bsum, int* __restrict__ boffs, int B) {
  int t = threadIdx.x;
  int lane = t & 63, wid = t >> 6;
  int v = (t < B) ? bsum[t] : 0;
  int incl = v;
#pragma unroll
  for (int off = 1; off < 64; off <<= 1) {
    int u = __shfl_up(incl, off, 64);
    if (lane >= off) incl += u;
  }
  __shared__ int ws[2];
  if (lane == 63) ws[wid] = incl;
  __syncthreads();
  int base = (wid == 1) ? ws[0] : 0;
  if (t < B) boffs[t] = base + incl - v;
}

__global__ void ptrs_kernel(const int* __restrict__ deg, const int* __restrict__ boffs,
                            int* __restrict__ ptrs, int N) {
  int t = threadIdx.x;
  int i = blockIdx.x * 512 + t;
  int lane = t & 63, wid = t >> 6;
  int v = (i < N) ? deg[i] : 0;
  int incl = v;
#pragma unroll
  for (int off = 1; off < 64; off <<= 1) {
    int u = __shfl_up(incl, off, 64);
    if (lane >= off) incl += u;
  }
  __shared__ int ws[8];
  if (lane == 63) ws[wid] = incl;
  __syncthreads();
  if (t == 0) {
    int s = 0;
#pragma unroll
    for (int j = 0; j < 8; ++j) { int tmp = ws[j]; ws[j] = s; s += tmp; }
  }
  __syncthreads();
  if (i < N) ptrs[i + 1] = boffs[blockIdx.x] + ws[wid] + incl;
  if (i == 0 && blockIdx.x == 0) ptrs[0] = 0;
}

__global__ void fill_csr_kernel(const int* __restrict__ src, const int* __restrict__ dst,
                                const int* __restrict__ ptrs, int* __restrict__ cnt,
                                int* __restrict__ csr_src, int* __restrict__ csr_eid, int E) {
  int i = blockIdx.x * blockDim.x + threadIdx.x;
  if (i < E) {
    int d = dst[i];
    int pos = ptrs[d] + atomicAdd(&cnt[d], 1);
    csr_src[pos] = src[i];
    csr_eid[pos] = i;
  }
}

// ---------------- Layer-0 fused aggregation: ea (HBM) + x (L2/L3), one CSR pass ----------------
// One wave per node. ea: 4 slots x 16 lanes (float4, 2 accs); x: 8 slots x 8 lanes (short8).
// Both streams advance 8 edges per loop iteration. (round-8 proven structure)
__global__ __launch_bounds__(256) void agg0_kernel(
    const int* __restrict__ ptrs, const int* __restrict__ csr_src, const int* __restrict__ csr_eid,
    const float* __restrict__ ea, const unsigned short* __restrict__ xb,
    unsigned short* __restrict__ agge, unsigned short* __restrict__ aggx64, int N) {
  int t = threadIdx.x;
  int n = blockIdx.x * 4 + (t >> 6);
  if (n >= N) return;
  int lane = t & 63;
  int slot_a = lane >> 4, cg_a = lane & 15;  // ea role
  int slot_b = lane >> 3, cg_b = lane & 7;   // x role
  int s = ptrs[n], e = ptrs[n + 1];
  float4 z = make_float4(0, 0, 0, 0);
  float4 a0 = z, a1 = z;
  float4 xlo = z, xhi = z;
  int i = s;
  for (; i + 8 <= e; i += 8) {
    int e0 = csr_eid[i + slot_a];
    int e1 = csr_eid[i + 4 + slot_a];
    int r0 = csr_src[i + slot_b];
    a0 = add4(a0, *((const float4*)(ea + (size_t)e0 * 64) + cg_a));
    a1 = add4(a1, *((const float4*)(ea + (size_t)e1 * 64) + cg_a));
    acc8(xlo, xhi, *(const short8v*)(xb + (size_t)r0 * 64 + cg_b * 8));
  }
  if (i + slot_a < e)
    a0 = add4(a0, *((const float4*)(ea + (size_t)csr_eid[i + slot_a] * 64) + cg_a));
  if (i + 4 + slot_a < e)
    a1 = add4(a1, *((const float4*)(ea + (size_t)csr_eid[i + 4 + slot_a] * 64) + cg_a));
  if (i + slot_b < e)
    acc8(xlo, xhi, *(const short8v*)(xb + (size_t)csr_src[i + slot_b] * 64 + cg_b * 8));

  // ea reduce across 4 slots (lane bits 4,5)
  a0 = add4(a0, a1);
  a0 = add4(a0, shflx4(a0, 16));
  a0 = add4(a0, shflx4(a0, 32));
  if (slot_a == 0) {
    short4v o;
    o[0] = (short)f2bf(a0.x); o[1] = (short)f2bf(a0.y);
    o[2] = (short)f2bf(a0.z); o[3] = (short)f2bf(a0.w);
    *(short4v*)(agge + (size_t)n * 64 + cg_a * 4) = o;
  }
  // x reduce across 8 slots (lane bits 3,4,5)
  xlo = add4(xlo, shflx4(xlo, 8));  xhi = add4(xhi, shflx4(xhi, 8));
  xlo = add4(xlo, shflx4(xlo, 16)); xhi = add4(xhi, shflx4(xhi, 16));
  xlo = add4(xlo, shflx4(xlo, 32)); xhi = add4(xhi, shflx4(xhi, 32));
  if (slot_b == 0) {
    short8v o;
    o[0] = (short)f2bf(xlo.x); o[1] = (short)f2bf(xlo.y);
    o[2] = (short)f2bf(xlo.z); o[3] = (short)f2bf(xlo.w);
    o[4] = (short)f2bf(xhi.x); o[5] = (short)f2bf(xhi.y);
    o[6] = (short)f2bf(xhi.z); o[7] = (short)f2bf(xhi.w);
    *(short8v*)(aggx64 + (size_t)n * 64 + cg_b * 8) = o;
  }
}

// bf16 rows of 128 (256B); one wave per node; 4 slots x 16 lanes; 8 edges/iter.
__global__ __launch_bounds__(256) void agg_bf128_kernel(
    const int* __restrict__ ptrs, const int* __restrict__ csr_src,
    const unsigned short* __restrict__ xb, unsigned short* __restrict__ outagg, int N) {
  int t = threadIdx.x;
  int n = blockIdx.x * 4 + (t >> 6);
  if (n >= N) return;
  int lane = t & 63;
  int slot = lane >> 4, cg = lane & 15;
  int s = ptrs[n], e = ptrs[n + 1];
  float4 lo0 = make_float4(0, 0, 0, 0), hi0 = make_float4(0, 0, 0, 0);
  float4 lo1 = make_float4(0, 0, 0, 0), hi1 = make_float4(0, 0, 0, 0);
  int i = s + slot;
  for (; i + 4 < e; i += 8) {
    acc8(lo0, hi0, *(const short8v*)(xb + (size_t)csr_src[i] * 128 + cg * 8));
    acc8(lo1, hi1, *(const short8v*)(xb + (size_t)csr_src[i + 4] * 128 + cg * 8));
  }
  if (i < e) acc8(lo0, hi0, *(const short8v*)(xb + (size_t)csr_src[i] * 128 + cg * 8));
  lo0 = add4(lo0, lo1); hi0 = add4(hi0, hi1);
  lo0 = add4(lo0, shflx4(lo0, 16)); hi0 = add4(hi0, shflx4(hi0, 16));
  lo0 = add4(lo0, shflx4(lo0, 32)); hi0 = add4(hi0, shflx4(hi0, 32));
  if (slot == 0) {
    short8v o;
    o[0] = (short)f2bf(lo0.x); o[1] = (short)f2bf(lo0.y);
    o[2] = (short)f2bf(lo0.z); o[3] = (short)f2bf(lo0.w);
    o[4] = (short)f2bf(hi0.x); o[5] = (short)f2bf(hi0.y);
    o[6] = (short)f2bf(hi0.z); o[7] = (short)f2bf(hi0.w);
    *(short8v*)(outagg + (size_t)n * 128 + cg * 8) = o;
  }
}

// ---------------- MFMA fused transform (optionally with fused graph pooling) ----------------
template <int POOL>
__global__ __launch_bounds__(256) void gemm_mfma_kernel(
    const unsigned short* __restrict__ A1, int w1, int k1,
    const unsigned short* __restrict__ A2, int w2, int k2,
    const unsigned short* __restrict__ A3, int w3, int k3,
    const unsigned short* __restrict__ Wt, int Ktot,
    const float* __restrict__ be, const float* __restrict__ br,
    const int* __restrict__ deg, const int* __restrict__ batch,
    unsigned short* __restrict__ out, float* __restrict__ pout, int N) {
  int t = threadIdx.x;
  int wave = t >> 6, lane = t & 63;
  int rit = lane & 15, kgrp = lane >> 4;
  int n0 = blockIdx.x * 64;
  int arow = n0 + wave * 16 + rit;
  if (arow >= N) arow = N - 1;
  f32x4 acc[8];
#pragma unroll
  for (int c = 0; c < 8; ++c) acc[c] = (f32x4){0.f, 0.f, 0.f, 0.f};

  const unsigned short* As[3] = {A1, A2, A3};
  const int wds[3] = {w1, w2, w3};
  const int ks[3] = {k1, k2, k3};
  int kbase = 0;
  for (int s = 0; s < 3; ++s) {
    const unsigned short* Arow = As[s] + (size_t)arow * wds[s] + kgrp * 8;
    int K = ks[s];
    for (int kk = 0; kk < K; kk += 32) {
      short8v a = *(const short8v*)(Arow + kk);
      int kg = kbase + kk + kgrp * 8;
#pragma unroll
      for (int c = 0; c < 8; ++c) {
        short8v b = *(const short8v*)(Wt + (size_t)(c * 16 + rit) * Ktot + kg);
        acc[c] = __builtin_amdgcn_mfma_f32_16x16x32_bf16(a, b, acc[c], 0, 0, 0);
      }
    }
    kbase += K;
  }

  __shared__ unsigned short st[64][136];
  __shared__ int bsh[64];
  float dg[4];
#pragma unroll
  for (int r = 0; r < 4; ++r) {
    int n = n0 + wave * 16 + kgrp * 4 + r;
    dg[r] = (float)deg[n < N ? n : N - 1];
  }
#pragma unroll
  for (int c = 0; c < 8; ++c) {
    int col = c * 16 + rit;
    float bev = be[col], brv = br[col];
#pragma unroll
    for (int r = 0; r < 4; ++r) {
      float v = acc[c][r] + dg[r] * bev + brv;
      st[wave * 16 + kgrp * 4 + r][col] = f2bf(fmaxf(v, 0.f));
    }
  }
  if (POOL && t < 64) {
    int n = n0 + t;
    bsh[t] = (n < N) ? batch[n] : -1;
  }
  __syncthreads();

  if (POOL) {
    if (t < 128) {
      int c = t;
      float acc2 = 0.f;
      int g = bsh[0];
      for (int r = 0; r < 64; ++r) {
        int n = n0 + r;
        if (n >= N) break;
        int gn = bsh[r];
        if (gn != g) {
          atomicAdd(&pout[g * 128 + c], acc2);
          acc2 = 0.f;
          g = gn;
        }
        acc2 += bf2f(st[r][c]);
      }
      atomicAdd(&pout[g * 128 + c], acc2);
    }
  } else {
#pragma unroll
    for (int it = 0; it < 4; ++it) {
      int idx = t + it * 256;
      int row = idx >> 4, cg = idx & 15;
      int n = n0 + row;
      if (n < N)
        *(short8v*)(out + (size_t)n * 128 + cg * 8) = *(const short8v*)(&st[row][cg * 8]);
    }
  }
}

// ---------------- launch ----------------

extern "C" void kernel_launch(void* const* d_in, const int* in_sizes, int n_in,
                              void* d_out, int out_size, void* d_ws, size_t ws_size,
                              hipStream_t stream) {
  const float* x_in       = (const float*)d_in[0];
  const int*   edge_index = (const int*)d_in[1];
  const float* edge_attr  = (const float*)d_in[2];
  const int*   batch      = (const int*)d_in[3];
  const float* We0 = (const float*)d_in[4];
  const float* be0 = (const float*)d_in[5];
  const float* Wr0 = (const float*)d_in[6];
  const float* br0 = (const float*)d_in[7];
  const float* We1 = (const float*)d_in[8];
  const float* be1 = (const float*)d_in[9];
  const float* Wr1 = (const float*)d_in[10];
  const float* br1 = (const float*)d_in[11];
  const float* We2 = (const float*)d_in[12];
  const float* be2 = (const float*)d_in[13];
  const float* Wr2 = (const float*)d_in[14];
  const float* br2 = (const float*)d_in[15];

  float* out = (float*)d_out;

  int N = in_sizes[0] / 64;   // 50000
  int E = in_sizes[1] / 2;    // 1600000
  const int* src = edge_index;
  const int* dst = edge_index + E;

  char* w = (char*)d_ws;
  size_t off = 0;
  auto alloc = [&](size_t bytes) {
    void* p = w + off;
    off += (bytes + 255) & ~(size_t)255;
    return p;
  };
  int* deg     = (int*)alloc((size_t)N * 4);
  int* cnt     = (int*)alloc((size_t)N * 4);
  size_t zero_bytes = off;  // deg + cnt zeroed each call
  int* ptrs    = (int*)alloc((size_t)(N + 1) * 4);
  int* bsum    = (int*)alloc(128 * 4);
  int* boffs   = (int*)alloc(128 * 4);
  int* csr_src = (int*)alloc((size_t)E * 4);
  int* csr_eid = (int*)alloc((size_t)E * 4);
  unsigned short* x_bf   = (unsigned short*)alloc((size_t)N * 64 * 2);
  unsigned short* aggx64 = (unsigned short*)alloc((size_t)N * 64 * 2);
  unsigned short* agge   = (unsigned short*)alloc((size_t)N * 64 * 2);
  unsigned short* aggx   = (unsigned short*)alloc((size_t)N * 128 * 2);
  unsigned short* xb0    = (unsigned short*)alloc((size_t)N * 128 * 2);
  unsigned short* xb1    = (unsigned short*)alloc((size_t)N * 128 * 2);
  unsigned short* Wt0    = (unsigned short*)alloc((size_t)128 * 192 * 2);
  unsigned short* Wt1    = (unsigned short*)alloc((size_t)128 * 320 * 2);
  unsigned short* Wt2    = (unsigned short*)alloc((size_t)128 * 320 * 2);

  (void)hipMemsetAsync(d_ws, 0, zero_bytes, stream);
  (void)hipMemsetAsync(d_out, 0, (size_t)out_size * sizeof(float), stream);

  int eb = (E + 255) / 256;
  int sb = (N + 511) / 512;  // 98 blocks (<=128 required by scan_small)
  prep_kernel<<<2048, 256, 0, stream>>>(dst, deg, E, x_in, x_bf, N * 64 / 8,
                                        We0, Wr0, We1, Wr1, We2, Wr2, Wt0, Wt1, Wt2);
  block_sum_kernel<<<sb, 512, 0, stream>>>(deg, bsum, N);
  scan_small_kernel<<<1, 128, 0, stream>>>(bsum, boffs, sb);
  ptrs_kernel<<<sb, 512, 0, stream>>>(deg, boffs, ptrs, N);
  fill_csr_kernel<<<eb, 256, 0, stream>>>(src, dst, ptrs, cnt, csr_src, csr_eid, E);

  int gb = (N + 63) / 64;
  int ab = (N + 3) / 4;

  // Layer-0 aggregation: edge_attr (layer-invariant) + x, one CSR pass
  agg0_kernel<<<ab, 256, 0, stream>>>(ptrs, csr_src, csr_eid, edge_attr, x_bf, agge, aggx64, N);

  // Layer 0: K-order (aggx64:We0[0:64], agge:We0[64:128], x:Wr0)
  gemm_mfma_kernel<0><<<gb, 256, 0, stream>>>(aggx64, 64, 64, agge, 64, 64, x_bf, 64, 64,
                                              Wt0, 192, be0, br0, deg, batch, xb0, nullptr, N);
  // Layer 1
  agg_bf128_kernel<<<ab, 256, 0, stream>>>(ptrs, csr_src, xb0, aggx, N);
  gemm_mfma_kernel<0><<<gb, 256, 0, stream>>>(aggx, 128, 128, agge, 64, 64, xb0, 128, 128,
                                              Wt1, 320, be1, br1, deg, batch, xb1, nullptr, N);
  // Layer 2 + fused readout pooling
  agg_bf128_kernel<<<ab, 256, 0, stream>>>(ptrs, csr_src, xb1, aggx, N);
  gemm_mfma_kernel<1><<<gb, 256, 0, stream>>>(aggx, 128, 128, agge, 64, 64, xb1, 128, 128,
                                              Wt2, 320, be2, br2, deg, batch, nullptr, out, N);
}